// Round 12
// baseline (225.728 us; speedup 1.0000x reference)
//
#include <hip/hip_runtime.h>
#include <hip/hip_bf16.h>

#define SEQ 4096
#define BATCH 2
#define HEADS 16
#define DHEAD 64
#define HID 1024

typedef unsigned short ushort_t;
typedef unsigned int uint_t;
typedef __attribute__((ext_vector_type(8))) short short8;
typedef __attribute__((ext_vector_type(4))) float f32x4;
typedef __attribute__((ext_vector_type(16))) float f32x16;
typedef __attribute__((ext_vector_type(4))) uint_t u32x4;

__device__ __forceinline__ float exp2_fast(float x) {
  return __builtin_amdgcn_exp2f(x);  // v_exp_f32 computes 2^x natively
}

__device__ __forceinline__ float max3f(float a, float b, float c) {
  float r;
  asm("v_max3_f32 %0, %1, %2, %3" : "=v"(r) : "v"(a), "v"(b), "v"(c));
  return r;
}

__device__ __forceinline__ ushort_t f2b(float f) {
  unsigned u = __builtin_bit_cast(unsigned, f);
  unsigned r = 0x7fffu + ((u >> 16) & 1u);
  return (ushort_t)((u + r) >> 16);
}

__device__ __forceinline__ uint_t cvt_pk_bf16(float lo, float hi) {
  uint_t r;
  asm("v_cvt_pk_bf16_f32 %0, %1, %2" : "=v"(r) : "v"(lo), "v"(hi));
  return r;
}

// swap a's hi-32-lane half with b's lo-32-lane half (CDNA4 cross-lane, VALU pipe)
__device__ __forceinline__ void permlane_swap(uint_t& a, uint_t& b) {
  asm("v_permlane32_swap_b32 %0, %1" : "+v"(a), "+v"(b));
}

__device__ __forceinline__ void gload16(const void* g, void* l) {
  __builtin_amdgcn_global_load_lds((const __attribute__((address_space(1))) void*)g,
                                   (__attribute__((address_space(3))) void*)l, 16, 0, 0);
}

__device__ __forceinline__ f32x4 mfma_bf16(short8 a, short8 b, f32x4 c) {
  return __builtin_amdgcn_mfma_f32_16x16x32_bf16(a, b, c, 0, 0, 0);
}

__device__ __forceinline__ f32x16 mfma32_bf16(short8 a, short8 b, f32x16 c) {
  return __builtin_amdgcn_mfma_f32_32x32x16_bf16(a, b, c, 0, 0, 0);
}

// ---------------- fp32 -> bf16 elementwise (vectorized) ----------------
__global__ void cvt_kernel(const float* __restrict__ in, ushort_t* __restrict__ out, int n4) {
  int i = blockIdx.x * blockDim.x + threadIdx.x;
  if (i >= n4) return;
  float4 v = reinterpret_cast<const float4*>(in)[i];
  ushort4 o;
  o.x = f2b(v.x); o.y = f2b(v.y); o.z = f2b(v.z); o.w = f2b(v.w);
  reinterpret_cast<ushort4*>(out)[i] = o;
}

// ---------------- transpose + convert: in[rows][cols] f32 -> out[cols][rows] bf16 ----------------
__global__ void transpose_cvt_kernel(const float* __restrict__ in, ushort_t* __restrict__ out,
                                     int rows, int cols) {
  __shared__ float tile[32][33];
  int tx = threadIdx.x & 31, ty = threadIdx.x >> 5;
  int r0 = blockIdx.y * 32, c0 = blockIdx.x * 32;
#pragma unroll
  for (int i = 0; i < 32; i += 8)
    tile[ty + i][tx] = in[(size_t)(r0 + ty + i) * cols + c0 + tx];
  __syncthreads();
#pragma unroll
  for (int i = 0; i < 32; i += 8)
    out[(size_t)(c0 + ty + i) * rows + r0 + tx] = f2b(tile[tx][ty + i]);
}

// ---------------- bf16 GEMM: C = A[M][K] * BT[N][K]^T ----------------
// 1-D grid with bijective XCD-chunk swizzle (grid%8==0): consecutive blocks on
// one XCD share the B-panel -> L2 reuse. MODE 0: scatter-write q(*0.125*log2e)/
// k bf16 rows; V written via packed ushort4 (r-quad = 4 consecutive s).
// MODE 1: write fp32 C.
template <int MODE>
__global__ __launch_bounds__(256, 2)
void gemm_kernel(const ushort_t* __restrict__ A, const ushort_t* __restrict__ BT,
                 int M, int N, int K,
                 ushort_t* __restrict__ qg, ushort_t* __restrict__ kg,
                 ushort_t* __restrict__ vTg, float* __restrict__ outf) {
  __shared__ ushort_t lA[128 * 64];
  __shared__ ushort_t lB[128 * 64];
  int tid = threadIdx.x;
  int lane = tid & 63, w = tid >> 6;

  // XCD-chunk swizzle: each XCD owns a contiguous range of (n-panel, m) blocks
  int G = gridDim.x;
  int bid = blockIdx.x;
  int wg = (bid & 7) * (G >> 3) + (bid >> 3);
  int nbx = M >> 7;
  int m0 = (wg % nbx) * 128, n0 = (wg / nbx) * 128;

  int wr = (w >> 1) * 64, wc = (w & 1) * 64;
  int lr = lane & 15, lg = lane >> 4;

  const f32x4 z4 = {0.f, 0.f, 0.f, 0.f};
  f32x4 acc[4][4];
#pragma unroll
  for (int m = 0; m < 4; ++m)
#pragma unroll
    for (int n = 0; n < 4; ++n) acc[m][n] = z4;

  int ktiles = K >> 6;
  for (int kt = 0; kt < ktiles; ++kt) {
    int k0 = kt << 6;
#pragma unroll
    for (int i = 0; i < 4; ++i) {
      int c = i * 256 + tid;
      int row = c >> 3, cc = c & 7;
      gload16(A + (size_t)(m0 + row) * K + k0 + (cc ^ (row & 7)) * 8, lA + c * 8);
    }
#pragma unroll
    for (int i = 0; i < 4; ++i) {
      int c = i * 256 + tid;
      int row = c >> 3, cc = c & 7;
      gload16(BT + (size_t)(n0 + row) * K + k0 + (cc ^ (row & 7)) * 8, lB + c * 8);
    }
    __syncthreads();
#pragma unroll
    for (int kk = 0; kk < 2; ++kk) {
      short8 a[4], b[4];
#pragma unroll
      for (int m = 0; m < 4; ++m) {
        int row = wr + m * 16 + lr, cc = kk * 4 + lg;
        a[m] = *(const short8*)(lA + row * 64 + ((cc ^ (row & 7)) << 3));
      }
#pragma unroll
      for (int n = 0; n < 4; ++n) {
        int row = wc + n * 16 + lr, cc = kk * 4 + lg;
        b[n] = *(const short8*)(lB + row * 64 + ((cc ^ (row & 7)) << 3));
      }
      __builtin_amdgcn_s_setprio(1);
#pragma unroll
      for (int m = 0; m < 4; ++m)
#pragma unroll
        for (int n = 0; n < 4; ++n)
          acc[m][n] = mfma_bf16(a[m], b[n], acc[m][n]);
      __builtin_amdgcn_s_setprio(0);
    }
    __syncthreads();
  }

  if (MODE == 0) {
    int mat = n0 >> 10;                     // block-uniform (BN=128 divides 1024)
    int bq = m0 >> 12;                      // batch index, block-uniform
    int sbase = (m0 & 4095) + wr + lg * 4;  // per-thread s base
    if (mat == 2) {
      // V: vT[(bq*16+h)*64+d][s]; acc r-quad = 4 consecutive s -> ushort4 store
#pragma unroll
      for (int n = 0; n < 4; ++n) {
        int rem = wc + n * 16 + lr;         // n0&1023 == 0 for mat==2 blocks? no:
        rem += (n0 & 1023);                 // rem within [0,1024)
        int h = rem >> 6, d = rem & 63;
        ushort_t* dst = vTg + ((size_t)(bq * HEADS + h) * DHEAD + d) * SEQ;
#pragma unroll
        for (int m = 0; m < 4; ++m) {
          int s = sbase + m * 16;
          ushort4 pv;
          pv.x = f2b(acc[m][n][0]); pv.y = f2b(acc[m][n][1]);
          pv.z = f2b(acc[m][n][2]); pv.w = f2b(acc[m][n][3]);
          *(ushort4*)(dst + s) = pv;        // s % 4 == 0 -> 8B aligned
        }
      }
    } else {
      // Q (scaled by 0.125*log2e) or K: row-major [s][d]
      ushort_t* base = (mat == 0) ? qg : kg;
      float scale = (mat == 0) ? 0.18033688f : 1.0f;
#pragma unroll
      for (int n = 0; n < 4; ++n) {
        int rem = (n0 & 1023) + wc + n * 16 + lr;
        int h = rem >> 6, d = rem & 63;
        ushort_t* dst = base + (size_t)(bq * HEADS + h) * SEQ * DHEAD + d;
#pragma unroll
        for (int m = 0; m < 4; ++m)
#pragma unroll
          for (int r = 0; r < 4; ++r) {
            int s = sbase + m * 16 + r;
            dst[(size_t)s * DHEAD] = f2b(acc[m][n][r] * scale);
          }
      }
    }
  } else {
#pragma unroll
    for (int m = 0; m < 4; ++m)
#pragma unroll
      for (int n = 0; n < 4; ++n)
#pragma unroll
        for (int r = 0; r < 4; ++r) {
          int i = m0 + wr + m * 16 + lg * 4 + r;
          int j = n0 + wc + n * 16 + lr;
          outf[(size_t)i * N + j] = acc[m][n][r];
        }
  }
}

// ---------------- flash attention, 32x32 MFMA + in-register P ----------------
// One block per (bh, q-tile); grid 1024, XCD-pinned bh, heavy q-tiles first.
// LDS: lK dbuf 32KB + lV single 16KB = 48KB. Per iter: issue V(jt)+K(jt+1) ->
// QK+softmax (hides V latency) -> barrier -> PV -> barrier. P stays in
// registers (cvt_pk + permlane32_swap).
struct QS {
  short8 qf[4];
  f32x16 o[2];
  float mrow, lsum;
};

__device__ __forceinline__ void attn_qk_sm(int diag, int w, int l31, int hi, int lane,
                                           const ushort_t* lKc, QS& st, short8 (&pa)[8]) {
  f32x16 s[4];
#pragma unroll
  for (int t = 0; t < 4; ++t)
#pragma unroll
    for (int r = 0; r < 16; ++r) s[t][r] = 0.f;

  // S^T = K Q^T : tile t covers k = t*32..+31; contraction over d (4 x K=16)
#pragma unroll
  for (int t = 0; t < 4; ++t) {
    int row = t * 32 + l31;
#pragma unroll
    for (int kb = 0; kb < 4; ++kb) {
      int cc = kb * 2 + hi;
      short8 kf = *(const short8*)(lKc + row * 64 + ((cc ^ (row & 7)) << 3));
      __builtin_amdgcn_s_setprio(1);
      s[t] = mfma32_bf16(kf, st.qf[kb], s[t]);
      __builtin_amdgcn_s_setprio(0);
    }
  }

  if (diag) {  // causal mask, local indices (q0 == j0)
    int q = w * 32 + l31;
#pragma unroll
    for (int t = 0; t < 4; ++t)
#pragma unroll
      for (int r = 0; r < 16; ++r)
        if (t * 32 + (r & 3) + 8 * (r >> 2) + 4 * hi > q) s[t][r] = -1e30f;
  }

  // online softmax (exp2 domain); v_max3 tree, xor32 completes the row
  float mx = fmaxf(s[0][0], s[0][1]);
#pragma unroll
  for (int t = 0; t < 4; ++t)
#pragma unroll
    for (int r = (t == 0 ? 2 : 0); r < 16; r += 2)
      mx = max3f(mx, s[t][r], s[t][r + 1]);
  mx = fmaxf(mx, __shfl_xor(mx, 32));
  float mo = st.mrow;
  if (!__all(mx - mo <= 8.0f)) {  // defer-max THR=8
    float mn = fmaxf(mo, mx);
    float al = exp2_fast(mo - mn);
    st.mrow = mn;
    st.lsum *= al;
#pragma unroll
    for (int r = 0; r < 16; ++r) {
      float alo = __shfl(al, (r & 3) + 8 * (r >> 2) + 4 * hi);
      st.o[0][r] *= alo;
      st.o[1][r] *= alo;
    }
  }
  float mloc = st.mrow;
  // exp + sum: 4 parallel accumulation chains
  float rsv[4];
#pragma unroll
  for (int t = 0; t < 4; ++t) {
    float a = 0.f;
#pragma unroll
    for (int r = 0; r < 16; ++r) {
      float p = exp2_fast(s[t][r] - mloc);
      s[t][r] = p;
      a += p;
    }
    rsv[t] = a;
  }
  float rs = (rsv[0] + rsv[1]) + (rsv[2] + rsv[3]);
  rs += __shfl_xor(rs, 32);
  st.lsum += rs;

  // pack P -> bf16 A-fragments in registers (cvt_pk + permlane32_swap)
#pragma unroll
  for (int t = 0; t < 4; ++t) {
    uint_t w0 = cvt_pk_bf16(s[t][0], s[t][1]);
    uint_t w1 = cvt_pk_bf16(s[t][2], s[t][3]);
    uint_t w2 = cvt_pk_bf16(s[t][4], s[t][5]);
    uint_t w3 = cvt_pk_bf16(s[t][6], s[t][7]);
    permlane_swap(w0, w2);
    permlane_swap(w1, w3);
    u32x4 f0 = {w0, w1, w2, w3};
    pa[2 * t] = __builtin_bit_cast(short8, f0);
    uint_t w4 = cvt_pk_bf16(s[t][8], s[t][9]);
    uint_t w5 = cvt_pk_bf16(s[t][10], s[t][11]);
    uint_t w6 = cvt_pk_bf16(s[t][12], s[t][13]);
    uint_t w7 = cvt_pk_bf16(s[t][14], s[t][15]);
    permlane_swap(w4, w6);
    permlane_swap(w5, w7);
    u32x4 f1 = {w4, w5, w6, w7};
    pa[2 * t + 1] = __builtin_bit_cast(short8, f1);
  }
}

__device__ __forceinline__ void attn_pv(const ushort_t* lVc, int l31, int hi,
                                        const short8 (&pa)[8], QS& st) {
#pragma unroll
  for (int nd = 0; nd < 2; ++nd) {
    int row = nd * 32 + l31;
#pragma unroll
    for (int kb = 0; kb < 8; ++kb) {
      int cc = kb * 2 + hi;
      short8 vf = *(const short8*)(lVc + row * 128 + ((cc ^ (row & 15)) << 3));
      __builtin_amdgcn_s_setprio(1);
      st.o[nd] = mfma32_bf16(pa[kb], vf, st.o[nd]);
      __builtin_amdgcn_s_setprio(0);
    }
  }
}

__device__ __forceinline__ void attn_epilogue(const QS& st, int q0, int bh,
                                              int w, int l31, int hi,
                                              ushort_t* __restrict__ og) {
  int b = bh >> 4, h = bh & 15;
#pragma unroll
  for (int r = 0; r < 16; ++r) {
    int qr = (r & 3) + 8 * (r >> 2) + 4 * hi;
    float ls = __shfl(st.lsum, qr);
    float inv = 1.0f / ls;
    int srow = q0 + w * 32 + qr;
#pragma unroll
    for (int nd = 0; nd < 2; ++nd) {
      int col = h * 64 + nd * 32 + l31;
      og[((size_t)b * SEQ + srow) * HID + col] = f2b(st.o[nd][r] * inv);
    }
  }
}

__global__ __launch_bounds__(256, 2)
void attn_kernel(const ushort_t* __restrict__ qg, const ushort_t* __restrict__ kg,
                 const ushort_t* __restrict__ vTg, ushort_t* __restrict__ og) {
  __shared__ ushort_t lK[2][128 * 64];  // 32KB (K double-buffer)
  __shared__ ushort_t lV[64 * 128];     // 16KB (V single, also Q staging)

  int bid = blockIdx.x;
  // XCD-pinned bh (4 per XCD) + heavy q-tiles dispatched first
  int xcd = bid & 7, idx = bid >> 3;
  int bh = xcd * 4 + (idx & 3);
  int qt = 31 - (idx >> 2);
  int q0 = qt * 128;
  const ushort_t* Q = qg + (size_t)bh * SEQ * DHEAD;
  const ushort_t* Kp = kg + (size_t)bh * SEQ * DHEAD;
  const ushort_t* Vt = vTg + (size_t)bh * DHEAD * SEQ;

  int tid = threadIdx.x, lane = tid & 63, w = tid >> 6;
  int l31 = lane & 31, hi = lane >> 5;

  // prologue: stage Q -> lV, K0 -> lK[0] in one burst
#pragma unroll
  for (int i = 0; i < 4; ++i) {
    int c = i * 256 + tid;
    int row = c >> 3, cc = c & 7;
    size_t off = (cc ^ (row & 7)) * 8;
    gload16(Q + (size_t)(q0 + row) * DHEAD + off, &lV[c * 8]);
    gload16(Kp + (size_t)row * DHEAD + off, &lK[0][c * 8]);
  }
  __syncthreads();  // drains Q + K0

  QS st;
  int qrow = w * 32 + l31;
#pragma unroll
  for (int kb = 0; kb < 4; ++kb) {
    int cc = kb * 2 + hi;
    st.qf[kb] = *(const short8*)(&lV[0] + qrow * 64 + ((cc ^ (qrow & 7)) << 3));
  }
  asm volatile("s_waitcnt lgkmcnt(0)");
  __syncthreads();  // all waves have Q in regs before lV is reused for V

  st.mrow = -1e30f; st.lsum = 0.f;
#pragma unroll
  for (int nd = 0; nd < 2; ++nd)
#pragma unroll
    for (int r = 0; r < 16; ++r) st.o[nd][r] = 0.f;

  for (int jt = 0; jt <= qt; ++jt) {
    int cur = jt & 1, nxt = cur ^ 1;
    // issue V(jt) into lV (latency hides under QK+softmax)
#pragma unroll
    for (int i = 0; i < 4; ++i) {
      int c = i * 256 + tid;
      int d = c >> 4, cc = c & 15;
      gload16(Vt + (size_t)d * SEQ + jt * 128 + (cc ^ (d & 15)) * 8, &lV[c * 8]);
    }
    // prefetch next K tile
    if (jt < qt) {
      int j0n = (jt + 1) * 128;
#pragma unroll
      for (int i = 0; i < 4; ++i) {
        int c = i * 256 + tid;
        int row = c >> 3, cc = c & 7;
        gload16(Kp + (size_t)(j0n + row) * DHEAD + (cc ^ (row & 7)) * 8, &lK[nxt][c * 8]);
      }
    }

    short8 pa[8];
    attn_qk_sm(jt == qt, w, l31, hi, lane, &lK[cur][0], st, pa);

    __syncthreads();  // drains V(jt) (and K(jt+1)); lV visible to all waves
    attn_pv(&lV[0], l31, hi, pa, st);
    __syncthreads();  // all waves done reading lV before next V issue
  }

  attn_epilogue(st, q0, bh, w, l31, hi, og);
}

extern "C" void kernel_launch(void* const* d_in, const int* in_sizes, int n_in,
                              void* d_out, int out_size, void* d_ws, size_t ws_size,
                              hipStream_t stream) {
  const float* x = (const float*)d_in[0];
  const float* wqkv = (const float*)d_in[1];
  const float* wout = (const float*)d_in[2];
  float* out = (float*)d_out;

  if (ws_size < 75497472u) return;  // need 75.5 MB scratch

  char* ws = (char*)d_ws;
  ushort_t* xb    = (ushort_t*)(ws);               // 8192x1024 bf16 (reused as attn out)
  ushort_t* wqkvT = (ushort_t*)(ws + 16777216);    // 3072x1024
  ushort_t* woutT = (ushort_t*)(ws + 23068672);    // 1024x1024
  ushort_t* qgb   = (ushort_t*)(ws + 25165824);    // [32][4096][64]
  ushort_t* kgb   = (ushort_t*)(ws + 41943040);    // [32][4096][64]
  ushort_t* vTb   = (ushort_t*)(ws + 58720256);    // [32][64][4096]
  ushort_t* ob    = xb;

  cvt_kernel<<<dim3(8192), dim3(256), 0, stream>>>(x, xb, 2097152);
  transpose_cvt_kernel<<<dim3(96, 32), dim3(256), 0, stream>>>(wqkv, wqkvT, 1024, 3072);
  transpose_cvt_kernel<<<dim3(32, 32), dim3(256), 0, stream>>>(wout, woutT, 1024, 1024);
  gemm_kernel<0><<<dim3(1536), dim3(256), 0, stream>>>(xb, wqkvT, 8192, 3072, 1024,
                                                       qgb, kgb, vTb, nullptr);
  attn_kernel<<<dim3(1024), dim3(256), 0, stream>>>(qgb, kgb, vTb, ob);
  gemm_kernel<1><<<dim3(512), dim3(256), 0, stream>>>(ob, woutT, 8192, 1024, 1024,
                                                      nullptr, nullptr, nullptr, out);
}

// Round 13
// 218.104 us; speedup vs baseline: 1.0350x; 1.0350x over previous
//
#include <hip/hip_runtime.h>
#include <hip/hip_bf16.h>

#define SEQ 4096
#define BATCH 2
#define HEADS 16
#define DHEAD 64
#define HID 1024

typedef unsigned short ushort_t;
typedef unsigned int uint_t;
typedef __attribute__((ext_vector_type(8))) short short8;
typedef __attribute__((ext_vector_type(4))) float f32x4;
typedef __attribute__((ext_vector_type(16))) float f32x16;
typedef __attribute__((ext_vector_type(4))) uint_t u32x4;

__device__ __forceinline__ float exp2_fast(float x) {
  return __builtin_amdgcn_exp2f(x);  // v_exp_f32 computes 2^x natively
}

__device__ __forceinline__ float max3f(float a, float b, float c) {
  float r;
  asm("v_max3_f32 %0, %1, %2, %3" : "=v"(r) : "v"(a), "v"(b), "v"(c));
  return r;
}

__device__ __forceinline__ ushort_t f2b(float f) {
  unsigned u = __builtin_bit_cast(unsigned, f);
  unsigned r = 0x7fffu + ((u >> 16) & 1u);
  return (ushort_t)((u + r) >> 16);
}

__device__ __forceinline__ uint_t cvt_pk_bf16(float lo, float hi) {
  uint_t r;
  asm("v_cvt_pk_bf16_f32 %0, %1, %2" : "=v"(r) : "v"(lo), "v"(hi));
  return r;
}

// swap a's hi-32-lane half with b's lo-32-lane half (CDNA4 cross-lane, VALU pipe)
__device__ __forceinline__ void permlane_swap(uint_t& a, uint_t& b) {
  asm("v_permlane32_swap_b32 %0, %1" : "+v"(a), "+v"(b));
}

__device__ __forceinline__ void gload16(const void* g, void* l) {
  __builtin_amdgcn_global_load_lds((const __attribute__((address_space(1))) void*)g,
                                   (__attribute__((address_space(3))) void*)l, 16, 0, 0);
}

__device__ __forceinline__ f32x4 mfma_bf16(short8 a, short8 b, f32x4 c) {
  return __builtin_amdgcn_mfma_f32_16x16x32_bf16(a, b, c, 0, 0, 0);
}

__device__ __forceinline__ f32x16 mfma32_bf16(short8 a, short8 b, f32x16 c) {
  return __builtin_amdgcn_mfma_f32_32x32x16_bf16(a, b, c, 0, 0, 0);
}

// ---------------- fp32 -> bf16 elementwise (vectorized) ----------------
__global__ void cvt_kernel(const float* __restrict__ in, ushort_t* __restrict__ out, int n4) {
  int i = blockIdx.x * blockDim.x + threadIdx.x;
  if (i >= n4) return;
  float4 v = reinterpret_cast<const float4*>(in)[i];
  ushort4 o;
  o.x = f2b(v.x); o.y = f2b(v.y); o.z = f2b(v.z); o.w = f2b(v.w);
  reinterpret_cast<ushort4*>(out)[i] = o;
}

// ---------------- transpose + convert: in[rows][cols] f32 -> out[cols][rows] bf16 ----------------
__global__ void transpose_cvt_kernel(const float* __restrict__ in, ushort_t* __restrict__ out,
                                     int rows, int cols) {
  __shared__ float tile[32][33];
  int tx = threadIdx.x & 31, ty = threadIdx.x >> 5;
  int r0 = blockIdx.y * 32, c0 = blockIdx.x * 32;
#pragma unroll
  for (int i = 0; i < 32; i += 8)
    tile[ty + i][tx] = in[(size_t)(r0 + ty + i) * cols + c0 + tx];
  __syncthreads();
#pragma unroll
  for (int i = 0; i < 32; i += 8)
    out[(size_t)(c0 + ty + i) * rows + r0 + tx] = f2b(tile[tx][ty + i]);
}

// ---------------- bf16 GEMM: C = A[M][K] * BT[N][K]^T (R11 proven form) ----------------
// MODE 0: scatter-write q(*0.125*log2e)/k/vT bf16.  MODE 1: write fp32 C.
template <int MODE>
__global__ __launch_bounds__(256, 2)
void gemm_kernel(const ushort_t* __restrict__ A, const ushort_t* __restrict__ BT,
                 int M, int N, int K,
                 ushort_t* __restrict__ qg, ushort_t* __restrict__ kg,
                 ushort_t* __restrict__ vTg, float* __restrict__ outf) {
  __shared__ ushort_t lA[128 * 64];
  __shared__ ushort_t lB[128 * 64];
  int tid = threadIdx.x;
  int lane = tid & 63, w = tid >> 6;
  int m0 = blockIdx.x * 128, n0 = blockIdx.y * 128;
  int wr = (w >> 1) * 64, wc = (w & 1) * 64;
  int lr = lane & 15, lg = lane >> 4;

  const f32x4 z4 = {0.f, 0.f, 0.f, 0.f};
  f32x4 acc[4][4];
#pragma unroll
  for (int m = 0; m < 4; ++m)
#pragma unroll
    for (int n = 0; n < 4; ++n) acc[m][n] = z4;

  int ktiles = K >> 6;
  for (int kt = 0; kt < ktiles; ++kt) {
    int k0 = kt << 6;
#pragma unroll
    for (int i = 0; i < 4; ++i) {
      int c = i * 256 + tid;
      int row = c >> 3, cc = c & 7;
      gload16(A + (size_t)(m0 + row) * K + k0 + (cc ^ (row & 7)) * 8, lA + c * 8);
    }
#pragma unroll
    for (int i = 0; i < 4; ++i) {
      int c = i * 256 + tid;
      int row = c >> 3, cc = c & 7;
      gload16(BT + (size_t)(n0 + row) * K + k0 + (cc ^ (row & 7)) * 8, lB + c * 8);
    }
    __syncthreads();
#pragma unroll
    for (int kk = 0; kk < 2; ++kk) {
      short8 a[4], b[4];
#pragma unroll
      for (int m = 0; m < 4; ++m) {
        int row = wr + m * 16 + lr, cc = kk * 4 + lg;
        a[m] = *(const short8*)(lA + row * 64 + ((cc ^ (row & 7)) << 3));
      }
#pragma unroll
      for (int n = 0; n < 4; ++n) {
        int row = wc + n * 16 + lr, cc = kk * 4 + lg;
        b[n] = *(const short8*)(lB + row * 64 + ((cc ^ (row & 7)) << 3));
      }
      __builtin_amdgcn_s_setprio(1);
#pragma unroll
      for (int m = 0; m < 4; ++m)
#pragma unroll
        for (int n = 0; n < 4; ++n)
          acc[m][n] = mfma_bf16(a[m], b[n], acc[m][n]);
      __builtin_amdgcn_s_setprio(0);
    }
    __syncthreads();
  }

#pragma unroll
  for (int m = 0; m < 4; ++m)
#pragma unroll
    for (int n = 0; n < 4; ++n)
#pragma unroll
      for (int r = 0; r < 4; ++r) {
        int i = m0 + wr + m * 16 + lg * 4 + r;
        int j = n0 + wc + n * 16 + lr;
        float v = acc[m][n][r];
        if (MODE == 0) {
          int mat = j >> 10, rem = j & 1023;
          int h = rem >> 6, d = rem & 63;
          int b = i >> 12, s = i & 4095;
          int bh = b * HEADS + h;
          // fold 1/sqrt(64) * log2(e) into Q (softmax runs in exp2 domain)
          ushort_t val = f2b(mat == 0 ? v * 0.18033688f : v);
          if (mat == 0)      qg[((size_t)bh * SEQ + s) * DHEAD + d] = val;
          else if (mat == 1) kg[((size_t)bh * SEQ + s) * DHEAD + d] = val;
          else               vTg[((size_t)bh * DHEAD + d) * SEQ + s] = val;
        } else {
          outf[(size_t)i * N + j] = v;
        }
      }
}

// ---------------- flash attention, 32x32 MFMA + in-register P + MFMA row-sum ----------------
// One block per (bh, q-tile); grid 1024, XCD-pinned bh, heavy q-tiles first.
// LDS: lK dbuf 32KB + lV single 16KB = 48KB. Per iter: issue V(jt)+K(jt+1) ->
// QK+softmax (hides V latency) -> barrier -> PV -> barrier. P in registers
// (cvt_pk + permlane32_swap). Softmax denominator l = P*1 computed on the
// MATRIX pipe (ones-operand mfma into lacc, o-register layout) -- removes the
// 64-add VALU sum and all lsum shuffles.
struct QS {
  short8 qf[4];
  f32x16 o[2];
  f32x16 lacc;   // row-sum accumulator, same layout as o (regs=q, lanes dup)
  float mrow;
};

__device__ __forceinline__ void attn_qk_sm(int diag, int w, int l31, int hi, int lane,
                                           const ushort_t* lKc, QS& st, short8 (&pa)[8]) {
  f32x16 s[4];
#pragma unroll
  for (int t = 0; t < 4; ++t)
#pragma unroll
    for (int r = 0; r < 16; ++r) s[t][r] = 0.f;

  // S^T = K Q^T : tile t covers k = t*32..+31; contraction over d (4 x K=16)
#pragma unroll
  for (int t = 0; t < 4; ++t) {
    int row = t * 32 + l31;
#pragma unroll
    for (int kb = 0; kb < 4; ++kb) {
      int cc = kb * 2 + hi;
      short8 kf = *(const short8*)(lKc + row * 64 + ((cc ^ (row & 7)) << 3));
      __builtin_amdgcn_s_setprio(1);
      s[t] = mfma32_bf16(kf, st.qf[kb], s[t]);
      __builtin_amdgcn_s_setprio(0);
    }
  }

  if (diag) {  // causal mask, local indices (q0 == j0)
    int q = w * 32 + l31;
#pragma unroll
    for (int t = 0; t < 4; ++t)
#pragma unroll
      for (int r = 0; r < 16; ++r)
        if (t * 32 + (r & 3) + 8 * (r >> 2) + 4 * hi > q) s[t][r] = -1e30f;
  }

  // online softmax (exp2 domain); v_max3 tree, xor32 completes the row
  float mx = fmaxf(s[0][0], s[0][1]);
#pragma unroll
  for (int t = 0; t < 4; ++t)
#pragma unroll
    for (int r = (t == 0 ? 2 : 0); r < 16; r += 2)
      mx = max3f(mx, s[t][r], s[t][r + 1]);
  mx = fmaxf(mx, __shfl_xor(mx, 32));
  float mo = st.mrow;
  if (!__all(mx - mo <= 8.0f)) {  // defer-max THR=8
    float mn = fmaxf(mo, mx);
    float al = exp2_fast(mo - mn);
    st.mrow = mn;
#pragma unroll
    for (int r = 0; r < 16; ++r) {
      float alo = __shfl(al, (r & 3) + 8 * (r >> 2) + 4 * hi);
      st.o[0][r] *= alo;
      st.o[1][r] *= alo;
      st.lacc[r] *= alo;
    }
  }
  float mloc = st.mrow;
#pragma unroll
  for (int t = 0; t < 4; ++t)
#pragma unroll
    for (int r = 0; r < 16; ++r)
      s[t][r] = exp2_fast(s[t][r] - mloc);

  // pack P -> bf16 A-fragments in registers (cvt_pk + permlane32_swap)
#pragma unroll
  for (int t = 0; t < 4; ++t) {
    uint_t w0 = cvt_pk_bf16(s[t][0], s[t][1]);
    uint_t w1 = cvt_pk_bf16(s[t][2], s[t][3]);
    uint_t w2 = cvt_pk_bf16(s[t][4], s[t][5]);
    uint_t w3 = cvt_pk_bf16(s[t][6], s[t][7]);
    permlane_swap(w0, w2);
    permlane_swap(w1, w3);
    u32x4 f0 = {w0, w1, w2, w3};
    pa[2 * t] = __builtin_bit_cast(short8, f0);
    uint_t w4 = cvt_pk_bf16(s[t][8], s[t][9]);
    uint_t w5 = cvt_pk_bf16(s[t][10], s[t][11]);
    uint_t w6 = cvt_pk_bf16(s[t][12], s[t][13]);
    uint_t w7 = cvt_pk_bf16(s[t][14], s[t][15]);
    permlane_swap(w4, w6);
    permlane_swap(w5, w7);
    u32x4 f1 = {w4, w5, w6, w7};
    pa[2 * t + 1] = __builtin_bit_cast(short8, f1);
  }
}

// PV + MFMA row-sum: 3 independent accumulation chains (o0, o1, lacc)
__device__ __forceinline__ void attn_pv(const ushort_t* lVc, int l31, int hi,
                                        const short8 (&pa)[8], const short8 ones8, QS& st) {
#pragma unroll
  for (int kb = 0; kb < 8; ++kb) {
    int cc = kb * 2 + hi;
    int row0 = l31, row1 = 32 + l31;
    short8 vf0 = *(const short8*)(lVc + row0 * 128 + ((cc ^ (row0 & 15)) << 3));
    short8 vf1 = *(const short8*)(lVc + row1 * 128 + ((cc ^ (row1 & 15)) << 3));
    __builtin_amdgcn_s_setprio(1);
    st.o[0] = mfma32_bf16(pa[kb], vf0, st.o[0]);
    st.lacc = mfma32_bf16(pa[kb], ones8, st.lacc);
    st.o[1] = mfma32_bf16(pa[kb], vf1, st.o[1]);
    __builtin_amdgcn_s_setprio(0);
  }
}

__device__ __forceinline__ void attn_epilogue(const QS& st, int q0, int bh,
                                              int w, int l31, int hi,
                                              ushort_t* __restrict__ og) {
  int b = bh >> 4, h = bh & 15;
#pragma unroll
  for (int r = 0; r < 16; ++r) {
    int qr = (r & 3) + 8 * (r >> 2) + 4 * hi;
    float inv = 1.0f / st.lacc[r];  // lacc already in o layout, no shfl
    int srow = q0 + w * 32 + qr;
#pragma unroll
    for (int nd = 0; nd < 2; ++nd) {
      int col = h * 64 + nd * 32 + l31;
      og[((size_t)b * SEQ + srow) * HID + col] = f2b(st.o[nd][r] * inv);
    }
  }
}

__global__ __launch_bounds__(256, 2)
void attn_kernel(const ushort_t* __restrict__ qg, const ushort_t* __restrict__ kg,
                 const ushort_t* __restrict__ vTg, ushort_t* __restrict__ og) {
  __shared__ ushort_t lK[2][128 * 64];  // 32KB (K double-buffer)
  __shared__ ushort_t lV[64 * 128];     // 16KB (V single, also Q staging)

  int bid = blockIdx.x;
  // XCD-pinned bh (4 per XCD) + heavy q-tiles dispatched first
  int xcd = bid & 7, idx = bid >> 3;
  int bh = xcd * 4 + (idx & 3);
  int qt = 31 - (idx >> 2);
  int q0 = qt * 128;
  const ushort_t* Q = qg + (size_t)bh * SEQ * DHEAD;
  const ushort_t* Kp = kg + (size_t)bh * SEQ * DHEAD;
  const ushort_t* Vt = vTg + (size_t)bh * DHEAD * SEQ;

  int tid = threadIdx.x, lane = tid & 63, w = tid >> 6;
  int l31 = lane & 31, hi = lane >> 5;

  short8 ones8;
#pragma unroll
  for (int i = 0; i < 8; ++i) ones8[i] = (short)0x3F80;  // bf16 1.0

  // prologue: stage Q -> lV, K0 -> lK[0] in one burst
#pragma unroll
  for (int i = 0; i < 4; ++i) {
    int c = i * 256 + tid;
    int row = c >> 3, cc = c & 7;
    size_t off = (cc ^ (row & 7)) * 8;
    gload16(Q + (size_t)(q0 + row) * DHEAD + off, &lV[c * 8]);
    gload16(Kp + (size_t)row * DHEAD + off, &lK[0][c * 8]);
  }
  __syncthreads();  // drains Q + K0

  QS st;
  int qrow = w * 32 + l31;
#pragma unroll
  for (int kb = 0; kb < 4; ++kb) {
    int cc = kb * 2 + hi;
    st.qf[kb] = *(const short8*)(&lV[0] + qrow * 64 + ((cc ^ (qrow & 7)) << 3));
  }
  asm volatile("s_waitcnt lgkmcnt(0)");
  __syncthreads();  // all waves have Q in regs before lV is reused for V

  st.mrow = -1e30f;
#pragma unroll
  for (int r = 0; r < 16; ++r) { st.o[0][r] = 0.f; st.o[1][r] = 0.f; st.lacc[r] = 0.f; }

  for (int jt = 0; jt <= qt; ++jt) {
    int cur = jt & 1, nxt = cur ^ 1;
    // issue V(jt) into lV (latency hides under QK+softmax)
#pragma unroll
    for (int i = 0; i < 4; ++i) {
      int c = i * 256 + tid;
      int d = c >> 4, cc = c & 15;
      gload16(Vt + (size_t)d * SEQ + jt * 128 + (cc ^ (d & 15)) * 8, &lV[c * 8]);
    }
    // prefetch next K tile
    if (jt < qt) {
      int j0n = (jt + 1) * 128;
#pragma unroll
      for (int i = 0; i < 4; ++i) {
        int c = i * 256 + tid;
        int row = c >> 3, cc = c & 7;
        gload16(Kp + (size_t)(j0n + row) * DHEAD + (cc ^ (row & 7)) * 8, &lK[nxt][c * 8]);
      }
    }

    short8 pa[8];
    attn_qk_sm(jt == qt, w, l31, hi, lane, &lK[cur][0], st, pa);

    __syncthreads();  // drains V(jt) (and K(jt+1)); lV visible to all waves
    attn_pv(&lV[0], l31, hi, pa, ones8, st);
    __syncthreads();  // all waves done reading lV before next V issue
  }

  attn_epilogue(st, q0, bh, w, l31, hi, og);
}

extern "C" void kernel_launch(void* const* d_in, const int* in_sizes, int n_in,
                              void* d_out, int out_size, void* d_ws, size_t ws_size,
                              hipStream_t stream) {
  const float* x = (const float*)d_in[0];
  const float* wqkv = (const float*)d_in[1];
  const float* wout = (const float*)d_in[2];
  float* out = (float*)d_out;

  if (ws_size < 75497472u) return;  // need 75.5 MB scratch

  char* ws = (char*)d_ws;
  ushort_t* xb    = (ushort_t*)(ws);               // 8192x1024 bf16 (reused as attn out)
  ushort_t* wqkvT = (ushort_t*)(ws + 16777216);    // 3072x1024
  ushort_t* woutT = (ushort_t*)(ws + 23068672);    // 1024x1024
  ushort_t* qgb   = (ushort_t*)(ws + 25165824);    // [32][4096][64]
  ushort_t* kgb   = (ushort_t*)(ws + 41943040);    // [32][4096][64]
  ushort_t* vTb   = (ushort_t*)(ws + 58720256);    // [32][64][4096]
  ushort_t* ob    = xb;

  cvt_kernel<<<dim3(8192), dim3(256), 0, stream>>>(x, xb, 2097152);
  transpose_cvt_kernel<<<dim3(96, 32), dim3(256), 0, stream>>>(wqkv, wqkvT, 1024, 3072);
  transpose_cvt_kernel<<<dim3(32, 32), dim3(256), 0, stream>>>(wout, woutT, 1024, 1024);
  gemm_kernel<0><<<dim3(64, 24), dim3(256), 0, stream>>>(xb, wqkvT, 8192, 3072, 1024,
                                                         qgb, kgb, vTb, nullptr);
  attn_kernel<<<dim3(1024), dim3(256), 0, stream>>>(qgb, kgb, vTb, ob);
  gemm_kernel<1><<<dim3(64, 8), dim3(256), 0, stream>>>(ob, woutT, 8192, 1024, 1024,
                                                        nullptr, nullptr, nullptr, out);
}